// Round 1
// baseline (765.196 us; speedup 1.0000x reference)
//
#include <hip/hip_runtime.h>
#include <math.h>

#define NBATCH 2048

// acc[ch] += a[j] * w[j].ch  for 4 input elems (a) x 4 output channels (w)
__device__ __forceinline__ void fma16(float* ac, const float4 a, const float4* w) {
  ac[0] = fmaf(a.x, w[0].x, ac[0]);
  ac[0] = fmaf(a.y, w[1].x, ac[0]);
  ac[0] = fmaf(a.z, w[2].x, ac[0]);
  ac[0] = fmaf(a.w, w[3].x, ac[0]);
  ac[1] = fmaf(a.x, w[0].y, ac[1]);
  ac[1] = fmaf(a.y, w[1].y, ac[1]);
  ac[1] = fmaf(a.z, w[2].y, ac[1]);
  ac[1] = fmaf(a.w, w[3].y, ac[1]);
  ac[2] = fmaf(a.x, w[0].z, ac[2]);
  ac[2] = fmaf(a.y, w[1].z, ac[2]);
  ac[2] = fmaf(a.z, w[2].z, ac[2]);
  ac[2] = fmaf(a.w, w[3].z, ac[2]);
  ac[3] = fmaf(a.x, w[0].w, ac[3]);
  ac[3] = fmaf(a.y, w[1].w, ac[3]);
  ac[3] = fmaf(a.z, w[2].w, ac[3]);
  ac[3] = fmaf(a.w, w[3].w, ac[3]);
}

// One workgroup (256 threads) per image; all activations live in LDS.
// LDS plan (floats):
//   sm_a[9216] : s1 padded [16][16][stride 36]  -> later reused as s3 [49][64]
//   sm_b[5508] : s2 padded [9][9][stride 68]
//   sm_c[900]  : xin padded [30][30]            -> later reused as red[256]+h[64]+lg[10]+le[10]
//   sm_w1[320] : w1 [9][32] + b1[32]
// total 63,776 B (< 64 KB) -> 2 blocks/CU.
__global__ __launch_bounds__(256) void cnn_fused(
    const float* __restrict__ xg,
    const float* __restrict__ w1g, const float* __restrict__ b1g,
    const float* __restrict__ w2g, const float* __restrict__ b2g,
    const float* __restrict__ w3g, const float* __restrict__ b3g,
    const float* __restrict__ wd1g, const float* __restrict__ bd1g,
    const float* __restrict__ wd2g, const float* __restrict__ bd2g,
    float* __restrict__ out)
{
  __shared__ __align__(16) float sm_a[9216];
  __shared__ __align__(16) float sm_b[5508];
  __shared__ __align__(16) float sm_c[900];
  __shared__ __align__(16) float sm_w1[320];

  const int t = threadIdx.x;
  const int b = blockIdx.x;

  float* xin  = sm_c;           // [30][30] zero-padded input
  float* s1   = sm_a;           // [(r*16+c)*36 + ci], ci<32, padded halo
  float* s2   = sm_b;           // [(r*9+c)*68 + ci],  ci<64, padded halo
  float* s3   = sm_a;           // [sp*64 + ci], sp<49  (aliases s1; s1 dead by then)
  float* red  = sm_c;           // [256]   (aliases xin; dead after stage 1)
  float* hvec = sm_c + 256;     // [64]
  float* lg   = sm_c + 320;     // [10]
  float* le   = sm_c + 336;     // [10]
  float* w1s  = sm_w1;          // [288] = [tap][c]
  float* b1s  = sm_w1 + 288;    // [32]

  // ---- init: zero padded buffers, stage w1 ----
  for (int i = t; i < 900;  i += 256) xin[i] = 0.f;
  for (int i = t; i < 9216; i += 256) s1[i]  = 0.f;
  for (int i = t; i < 5508; i += 256) s2[i]  = 0.f;
  for (int i = t; i < 288;  i += 256) w1s[i] = w1g[i];
  if (t < 32) b1s[t] = b1g[t];
  __syncthreads();

  // ---- load input image interior ----
  const float* xb = xg + (long)b * 784;
  for (int i = t; i < 784; i += 256) {
    int y = i / 28, x = i - y * 28;
    xin[(y + 1) * 30 + (x + 1)] = xb[i];
  }
  __syncthreads();

  // ---- stage 1: conv1 (1->32) + relu + maxpool2 -> s1 [14][14][32] (padded) ----
  for (int idx = t; idx < 14 * 14 * 32; idx += 256) {
    int c  = idx & 31;
    int sp = idx >> 5;
    int oy = sp / 14, ox = sp - oy * 14;
    float m = 0.f;                       // relu floor; relu(max)=max(relu)
    #pragma unroll
    for (int dy = 0; dy < 2; ++dy)
    #pragma unroll
    for (int dx = 0; dx < 2; ++dx) {
      int iy = 2 * oy + dy, ix = 2 * ox + dx;   // conv center in 28x28
      float acc = b1s[c];
      #pragma unroll
      for (int ky = 0; ky < 3; ++ky)
      #pragma unroll
      for (int kx = 0; kx < 3; ++kx)
        acc = fmaf(xin[(iy + ky) * 30 + (ix + kx)], w1s[(ky * 3 + kx) * 32 + c], acc);
      m = fmaxf(m, acc);
    }
    s1[((oy + 1) * 16 + (ox + 1)) * 36 + c] = m;
  }
  __syncthreads();

  // ---- stage 2: conv2 (32->64) + relu + maxpool2 -> s2 [7][7][64] (padded) ----
  {
    const int c0 = (t & 15) * 4;
    float bias[4];
    #pragma unroll
    for (int i = 0; i < 4; ++i) bias[i] = b2g[c0 + i];
    for (int sp = t >> 4; sp < 49; sp += 16) {
      int oy = sp / 7, ox = sp - oy * 7;
      float acc[4][4];                   // [pool pos][out ch]
      #pragma unroll
      for (int p = 0; p < 4; ++p)
        #pragma unroll
        for (int i = 0; i < 4; ++i) acc[p][i] = bias[i];
      for (int tap = 0; tap < 9; ++tap) {
        int ky = tap / 3, kx = tap - ky * 3;
        int rb = 2 * oy + ky;            // padded row (dy=0)
        int cb = 2 * ox + kx;
        #pragma unroll
        for (int ci = 0; ci < 32; ci += 4) {
          float4 w[4];
          #pragma unroll
          for (int j = 0; j < 4; ++j)
            w[j] = *(const float4*)(w2g + ((tap * 32 + ci + j) * 64 + c0));
          #pragma unroll
          for (int dy = 0; dy < 2; ++dy)
          #pragma unroll
          for (int dx = 0; dx < 2; ++dx) {
            const float4 a = *(const float4*)(s1 + ((rb + dy) * 16 + (cb + dx)) * 36 + ci);
            fma16(acc[dy * 2 + dx], a, w);
          }
        }
      }
      #pragma unroll
      for (int i = 0; i < 4; ++i) {
        float m = fmaxf(fmaxf(acc[0][i], acc[1][i]), fmaxf(acc[2][i], acc[3][i]));
        s2[((oy + 1) * 9 + (ox + 1)) * 68 + c0 + i] = fmaxf(m, 0.f);
      }
    }
  }
  __syncthreads();

  // ---- stage 3: conv3 (64->64) + relu -> s3 [49][64] (flat, no pad) ----
  {
    const int c0  = (t & 15) * 4;
    const int spb = t >> 4;              // 0..15
    int sps[4], oyk[4], oxk[4];
    bool act[4];
    float acc[4][4];                     // [spatial k][out ch]
    float bias[4];
    #pragma unroll
    for (int i = 0; i < 4; ++i) bias[i] = b3g[c0 + i];
    #pragma unroll
    for (int k = 0; k < 4; ++k) {
      int sp = spb + 16 * k;             // 0..63
      act[k] = sp < 49;
      sps[k] = act[k] ? sp : 48;
      oyk[k] = sps[k] / 7;
      oxk[k] = sps[k] - oyk[k] * 7;
      #pragma unroll
      for (int i = 0; i < 4; ++i) acc[k][i] = bias[i];
    }
    for (int tap = 0; tap < 9; ++tap) {
      int ky = tap / 3, kx = tap - ky * 3;
      int ab[4];
      #pragma unroll
      for (int k = 0; k < 4; ++k)
        ab[k] = ((oyk[k] + ky) * 9 + (oxk[k] + kx)) * 68;
      for (int ci = 0; ci < 64; ci += 4) {
        float4 w[4];
        #pragma unroll
        for (int j = 0; j < 4; ++j)
          w[j] = *(const float4*)(w3g + ((tap * 64 + ci + j) * 64 + c0));
        #pragma unroll
        for (int k = 0; k < 4; ++k) {
          const float4 a = *(const float4*)(s2 + ab[k] + ci);
          fma16(acc[k], a, w);
        }
      }
    }
    __syncthreads();                     // all stage-2/3 reads of s1/s2 done before s3 (=s1) write
    #pragma unroll
    for (int k = 0; k < 4; ++k)
      if (act[k]) {
        #pragma unroll
        for (int i = 0; i < 4; ++i)
          s3[sps[k] * 64 + c0 + i] = fmaxf(acc[k][i], 0.f);
      }
  }
  __syncthreads();

  // ---- stage 4: dense1 3136->64 + relu ----
  {
    const int o = t & 63, part = t >> 6;
    const int k0 = part * 784;
    float acc = 0.f;
    for (int j = 0; j < 784; j += 4) {
      const float4 a = *(const float4*)(s3 + k0 + j);
      acc = fmaf(a.x, wd1g[(long)(k0 + j    ) * 64 + o], acc);
      acc = fmaf(a.y, wd1g[(long)(k0 + j + 1) * 64 + o], acc);
      acc = fmaf(a.z, wd1g[(long)(k0 + j + 2) * 64 + o], acc);
      acc = fmaf(a.w, wd1g[(long)(k0 + j + 3) * 64 + o], acc);
    }
    red[t] = acc;
  }
  __syncthreads();
  if (t < 64) {
    float v = red[t] + red[64 + t] + red[128 + t] + red[192 + t] + bd1g[t];
    hvec[t] = fmaxf(v, 0.f);
  }
  __syncthreads();

  // ---- stage 5: dense2 64->10 + softmax ----
  if (t < 10) {
    float acc = bd2g[t];
    #pragma unroll
    for (int k = 0; k < 64; ++k) acc = fmaf(hvec[k], wd2g[k * 10 + t], acc);
    lg[t] = acc;
  }
  __syncthreads();
  if (t < 10) {
    float m = lg[0];
    #pragma unroll
    for (int i = 1; i < 10; ++i) m = fmaxf(m, lg[i]);
    le[t] = expf(lg[t] - m);
  }
  __syncthreads();
  if (t < 10) {
    float s = 0.f;
    #pragma unroll
    for (int i = 0; i < 10; ++i) s += le[i];
    out[(long)b * 10 + t] = le[t] / s;
  }
}

extern "C" void kernel_launch(void* const* d_in, const int* in_sizes, int n_in,
                              void* d_out, int out_size, void* d_ws, size_t ws_size,
                              hipStream_t stream) {
  (void)in_sizes; (void)n_in; (void)d_ws; (void)ws_size; (void)out_size;
  const float* x   = (const float*)d_in[0];
  const float* w1  = (const float*)d_in[1];
  const float* b1  = (const float*)d_in[2];
  const float* w2  = (const float*)d_in[3];
  const float* b2  = (const float*)d_in[4];
  const float* w3  = (const float*)d_in[5];
  const float* b3  = (const float*)d_in[6];
  const float* wd1 = (const float*)d_in[7];
  const float* bd1 = (const float*)d_in[8];
  const float* wd2 = (const float*)d_in[9];
  const float* bd2 = (const float*)d_in[10];
  float* out = (float*)d_out;
  hipLaunchKernelGGL(cnn_fused, dim3(NBATCH), dim3(256), 0, stream,
                     x, w1, b1, w2, b2, w3, b3, wd1, bd1, wd2, bd2, out);
}

// Round 2
// 517.461 us; speedup vs baseline: 1.4788x; 1.4788x over previous
//
#include <hip/hip_runtime.h>
#include <math.h>

#define NBATCH 2048

// LDS plan (floats), total 9749 = 38,996 B -> 4 blocks/CU:
//   region A [0,6500):   s1 [196 pos][stride 33] + 32-float zero slot @6468
//                        later reused as s3 [49][64] (3136)
//   region B [6500,9749): xin [30][31]=930  (dead after stage1)
//                        then s2 [49][65]=3185 + 64-float zero slot @3185
//                        then red[1024] + hv[64] + lg[10] + le[10]
__global__ __launch_bounds__(256, 4) void cnn_fused(
    const float* __restrict__ xg,
    const float* __restrict__ w1g, const float* __restrict__ b1g,
    const float* __restrict__ w2g, const float* __restrict__ b2g,
    const float* __restrict__ w3g, const float* __restrict__ b3g,
    const float* __restrict__ wd1g, const float* __restrict__ bd1g,
    const float* __restrict__ wd2g, const float* __restrict__ bd2g,
    float* __restrict__ out)
{
  __shared__ __align__(16) float sm[9749];
  const int t = threadIdx.x;
  const int b = blockIdx.x;

  float* s1  = sm;            // [p*33 + c], zero slot @6468..6500
  float* s3  = sm;            // [sp*64 + c] (aliases s1, s1 dead)
  float* xin = sm + 6500;     // [30][31]
  float* s2  = sm + 6500;     // [sp*65 + c], zero slot @3185..3249 (aliases xin)
  float* red = sm + 6500;     // [16][64] partials (aliases s2, s2 dead)
  float* hv  = sm + 6500 + 1024;
  float* lg  = sm + 6500 + 1088;
  float* le  = sm + 6500 + 1098;

  // ---- phase 0: zero xin (incl. halo ring) + zero slots ----
  for (int i = t; i < 930; i += 256) xin[i] = 0.f;
  if (t < 32) s1[6468 + t] = 0.f;
  if (t >= 64 && t < 128) s2[3185 + (t - 64)] = 0.f;
  __syncthreads();

  // ---- phase 1: load input interior ----
  const float* xb = xg + (long)b * 784;
  for (int i = t; i < 784; i += 256) {
    int y = i / 28, x = i - y * 28;
    xin[(y + 1) * 31 + (x + 1)] = xb[i];
  }
  __syncthreads();

  // ---- stage 1: conv1 (1->32) + relu + maxpool2 -> s1 [196][33] ----
  {
    const int c  = t & 31;
    const int pg = t >> 5;                  // 0..7
    float wr[9];
    #pragma unroll
    for (int j = 0; j < 9; ++j) wr[j] = w1g[j * 32 + c];
    const float bias = b1g[c];
    for (int p = pg; p < 196; p += 8) {
      int oy = p / 14, ox = p - oy * 14;
      int base = (2 * oy) * 31 + (2 * ox);  // 4x4 input window (halo-adjusted)
      float xw[16];
      #pragma unroll
      for (int r = 0; r < 4; ++r)
        #pragma unroll
        for (int cc = 0; cc < 4; ++cc)
          xw[r * 4 + cc] = xin[base + r * 31 + cc];
      float m = 0.f;                        // relu floor
      #pragma unroll
      for (int dy = 0; dy < 2; ++dy)
      #pragma unroll
      for (int dx = 0; dx < 2; ++dx) {
        float acc = bias;
        #pragma unroll
        for (int ky = 0; ky < 3; ++ky)
        #pragma unroll
        for (int kx = 0; kx < 3; ++kx)
          acc = fmaf(xw[(dy + ky) * 4 + (dx + kx)], wr[ky * 3 + kx], acc);
        m = fmaxf(m, acc);
      }
      s1[p * 33 + c] = m;
    }
  }
  __syncthreads();

  // ---- stage 2: conv2 (32->64) + relu + maxpool2 -> s2 [49][65] ----
  // thread = conv position (sp 0..48, pool quadrant q 0..3); acc = all 64 out ch.
  // weight addresses are wave-uniform -> s_load into SGPRs; activation = 1 ds_read.
  {
    const int sp = t >> 2;                  // 0..63 (49 live)
    const int q  = t & 3;
    const int py = q >> 1, px = q & 1;
    const bool live = (sp < 49);
    const int oyp = sp / 7, oxp = sp - oyp * 7;
    const int y = 2 * oyp + py, x = 2 * oxp + px;   // conv pos in 14x14
    float acc[64];
    #pragma unroll
    for (int c = 0; c < 64; ++c) acc[c] = b2g[c];
    #pragma unroll 1
    for (int tap = 0; tap < 9; ++tap) {
      const int ky = tap / 3, kx = tap - ky * 3;
      int Y = y + ky - 1, X = x + kx - 1;
      bool v = live && ((unsigned)Y < 14u) && ((unsigned)X < 14u);
      int base = v ? (Y * 14 + X) * 33 : 6468;      // zero slot if OOB
      const float* wt = w2g + tap * (32 * 64);
      #pragma unroll 1
      for (int ci = 0; ci < 32; ++ci) {
        float a = s1[base + ci];
        const float* wrow = wt + ci * 64;           // uniform
        #pragma unroll
        for (int c = 0; c < 64; ++c)
          acc[c] = fmaf(a, wrow[c], acc[c]);
      }
    }
    // 2x2 maxpool across lanes (q in low 2 bits), relu, write pooled
    #pragma unroll
    for (int c0 = 0; c0 < 64; c0 += 4) {
      float r0[4];
      #pragma unroll
      for (int i = 0; i < 4; ++i) {
        float v = acc[c0 + i];
        v = fmaxf(v, __shfl_xor(v, 1));
        v = fmaxf(v, __shfl_xor(v, 2));
        r0[i] = fmaxf(v, 0.f);
      }
      if (live && q == 0) {
        s2[sp * 65 + c0]     = r0[0];
        s2[sp * 65 + c0 + 1] = r0[1];
        s2[sp * 65 + c0 + 2] = r0[2];
        s2[sp * 65 + c0 + 3] = r0[3];
      }
    }
  }
  __syncthreads();

  // ---- stage 3: conv3 (64->64) + relu -> s3 [49][64] ----
  // lane = position (49 of 64), wave = 16-channel group.
  {
    const int lane = t & 63;
    const int wv = __builtin_amdgcn_readfirstlane(t >> 6);
    const int c0 = wv * 16;
    const bool live = lane < 49;
    const int sy = lane / 7, sx = lane - sy * 7;
    float acc[16];
    #pragma unroll
    for (int i = 0; i < 16; ++i) acc[i] = b3g[c0 + i];
    #pragma unroll 1
    for (int tap = 0; tap < 9; ++tap) {
      const int ky = tap / 3, kx = tap - ky * 3;
      int Y = sy + ky - 1, X = sx + kx - 1;
      bool v = live && ((unsigned)Y < 7u) && ((unsigned)X < 7u);
      int base = v ? (Y * 7 + X) * 65 : 3185;       // zero slot if OOB
      const float* wt = w3g + tap * (64 * 64) + c0;
      #pragma unroll 1
      for (int ci = 0; ci < 64; ++ci) {
        float a = s2[base + ci];
        const float* wrow = wt + ci * 64;           // uniform
        #pragma unroll
        for (int i = 0; i < 16; ++i)
          acc[i] = fmaf(a, wrow[i], acc[i]);
      }
    }
    if (live) {
      #pragma unroll
      for (int i = 0; i < 16; i += 4) {
        float4 vv = make_float4(fmaxf(acc[i], 0.f), fmaxf(acc[i + 1], 0.f),
                                fmaxf(acc[i + 2], 0.f), fmaxf(acc[i + 3], 0.f));
        *(float4*)(s3 + lane * 64 + c0 + i) = vv;   // s1 dead; barrier above covers
      }
    }
  }
  __syncthreads();

  // ---- stage 4: dense1 3136->64 + relu ----
  // thread = (o-quad 0..15, k-part 0..15); 196 k each; float4 weights, 4:1 FMA:VMEM
  {
    const int oq = (t & 15) * 4;
    const int kp = t >> 4;
    const float* wp = wd1g + (long)kp * 196 * 64 + oq;
    const float* ap = s3 + kp * 196;
    float a0 = 0.f, a1 = 0.f, a2 = 0.f, a3 = 0.f;
    #pragma unroll 4
    for (int k = 0; k < 196; ++k) {
      float a = ap[k];
      const float4 w = *(const float4*)(wp + (long)k * 64);
      a0 = fmaf(a, w.x, a0);
      a1 = fmaf(a, w.y, a1);
      a2 = fmaf(a, w.z, a2);
      a3 = fmaf(a, w.w, a3);
    }
    *(float4*)(red + kp * 64 + oq) = make_float4(a0, a1, a2, a3);
  }
  __syncthreads();
  if (t < 64) {
    float s = bd1g[t];
    #pragma unroll
    for (int kp = 0; kp < 16; ++kp) s += red[kp * 64 + t];
    hv[t] = fmaxf(s, 0.f);
  }
  __syncthreads();

  // ---- stage 5: dense2 64->10 + softmax ----
  if (t < 10) {
    float a = bd2g[t];
    #pragma unroll
    for (int k = 0; k < 64; ++k) a = fmaf(hv[k], wd2g[k * 10 + t], a);
    lg[t] = a;
  }
  __syncthreads();
  if (t < 10) {
    float m = lg[0];
    #pragma unroll
    for (int i = 1; i < 10; ++i) m = fmaxf(m, lg[i]);
    le[t] = expf(lg[t] - m);
  }
  __syncthreads();
  if (t < 10) {
    float s = 0.f;
    #pragma unroll
    for (int i = 0; i < 10; ++i) s += le[i];
    out[(long)b * 10 + t] = le[t] / s;
  }
}

extern "C" void kernel_launch(void* const* d_in, const int* in_sizes, int n_in,
                              void* d_out, int out_size, void* d_ws, size_t ws_size,
                              hipStream_t stream) {
  (void)in_sizes; (void)n_in; (void)d_ws; (void)ws_size; (void)out_size;
  const float* x   = (const float*)d_in[0];
  const float* w1  = (const float*)d_in[1];
  const float* b1  = (const float*)d_in[2];
  const float* w2  = (const float*)d_in[3];
  const float* b2  = (const float*)d_in[4];
  const float* w3  = (const float*)d_in[5];
  const float* b3  = (const float*)d_in[6];
  const float* wd1 = (const float*)d_in[7];
  const float* bd1 = (const float*)d_in[8];
  const float* wd2 = (const float*)d_in[9];
  const float* bd2 = (const float*)d_in[10];
  float* out = (float*)d_out;
  hipLaunchKernelGGL(cnn_fused, dim3(NBATCH), dim3(256), 0, stream,
                     x, w1, b1, w2, b2, w3, b3, wd1, bd1, wd2, bd2, out);
}

// Round 3
// 262.636 us; speedup vs baseline: 2.9135x; 1.9703x over previous
//
#include <hip/hip_runtime.h>
#include <math.h>

#define NBATCH 2048

typedef unsigned short ushortT;
typedef __attribute__((ext_vector_type(8))) short bf16x8;
typedef __attribute__((ext_vector_type(4))) float f32x4;

__device__ __forceinline__ ushortT f2bf(float f) {
  union { float f; unsigned u; } v; v.f = f;
  unsigned r = v.u + 0x7FFF + ((v.u >> 16) & 1);
  return (ushortT)(r >> 16);
}
__device__ __forceinline__ float bf2f(ushortT h) {
  union { float f; unsigned u; } v; v.u = ((unsigned)h) << 16; return v.f;
}

// ---- prep: w2 [9][32][64] -> w2t hi/lo [tap][co][ci]; w3 [9][64][64] -> w3t hi/lo.
// ws ushort layout: w2t_hi [0,18432) w2t_lo [18432,36864) w3t_hi [36864,73728) w3t_lo [73728,110592)
__global__ __launch_bounds__(256) void prep_w(const float* __restrict__ w2,
                                              const float* __restrict__ w3,
                                              ushortT* __restrict__ ws) {
  int i = blockIdx.x * 256 + threadIdx.x;
  if (i < 18432) {
    int tap = i / 2048, r = i - tap * 2048, ci = r >> 6, co = r & 63;
    float w = w2[i];
    ushortT hb = f2bf(w);
    ushortT lb = f2bf(w - bf2f(hb));
    int o = (tap * 64 + co) * 32 + ci;
    ws[o] = hb; ws[18432 + o] = lb;
  } else if (i < 55296) {
    int j = i - 18432;
    int tap = j >> 12, r = j & 4095, ci = r >> 6, co = r & 63;
    float w = w3[j];
    ushortT hb = f2bf(w);
    ushortT lb = f2bf(w - bf2f(hb));
    int o = (tap * 64 + co) * 64 + ci;
    ws[36864 + o] = hb; ws[73728 + o] = lb;
  }
}

// ---- fused conv1+pool (fp32 VALU) -> conv2+pool (MFMA) -> conv3 (MFMA) per image.
// s1 grid: [15..16 rows x 16 cols zero-halo][40 ushort stride] rows=(iy+1)*16+(ix+1), 240 rows
// s2 grid: [9x9 zero-halo][72 ushort stride] rows=(iy+1)*9+(ix+1), 81 rows
template<bool DENSE_IN>
__global__ __launch_bounds__(256, 4) void conv_fused(
    const float* __restrict__ xg,
    const float* __restrict__ w1g, const float* __restrict__ b1g,
    const float* __restrict__ b2g, const float* __restrict__ b3g,
    const ushortT* __restrict__ wsu, float* __restrict__ s3g,
    const float* __restrict__ wd1g, const float* __restrict__ bd1g,
    const float* __restrict__ wd2g, const float* __restrict__ bd2g,
    float* __restrict__ out)
{
  __shared__ __align__(16) ushortT s1u[240 * 40];   // 19200 B
  __shared__ __align__(16) ushortT s2u[81 * 72];    // 11664 B
  constexpr int FREG = DENSE_IN ? (3136 + 1024 + 64 + 10 + 10) : 930;
  __shared__ __align__(16) float fregion[FREG];

  const int t = threadIdx.x, b = blockIdx.x;
  float* xin = fregion;                              // [30][31] zero-padded

  // phase 0: zero LDS
  {
    unsigned* p1 = (unsigned*)s1u;
    unsigned* p2 = (unsigned*)s2u;
    for (int i = t; i < 4800; i += 256) p1[i] = 0u;
    for (int i = t; i < 2916; i += 256) p2[i] = 0u;
    for (int i = t; i < 930;  i += 256) xin[i] = 0.f;
  }
  __syncthreads();
  // phase 1: load image
  const float* xb = xg + (long)b * 784;
  for (int i = t; i < 784; i += 256) {
    int y = i / 28, x = i - y * 28;
    xin[(y + 1) * 31 + (x + 1)] = xb[i];
  }
  __syncthreads();

  // stage 1: conv1 (1->32) + relu + pool -> s1u bf16
  {
    const int c = t & 31, pg = t >> 5;
    float wr[9];
    #pragma unroll
    for (int j = 0; j < 9; ++j) wr[j] = w1g[j * 32 + c];
    const float bias = b1g[c];
    for (int p = pg; p < 196; p += 8) {
      int oy = p / 14, ox = p - oy * 14;
      int base = (2 * oy) * 31 + 2 * ox;
      float xw[16];
      #pragma unroll
      for (int r = 0; r < 4; ++r)
        #pragma unroll
        for (int cc = 0; cc < 4; ++cc) xw[r * 4 + cc] = xin[base + r * 31 + cc];
      float m = 0.f;
      #pragma unroll
      for (int dy = 0; dy < 2; ++dy)
      #pragma unroll
      for (int dx = 0; dx < 2; ++dx) {
        float acc = bias;
        #pragma unroll
        for (int ky = 0; ky < 3; ++ky)
        #pragma unroll
        for (int kx = 0; kx < 3; ++kx)
          acc = fmaf(xw[(dy + ky) * 4 + (dx + kx)], wr[ky * 3 + kx], acc);
        m = fmaxf(m, acc);
      }
      s1u[((oy + 1) * 16 + ox + 1) * 40 + c] = f2bf(m);
    }
  }
  __syncthreads();

  // stage 2: conv2 (32->64) via MFMA + in-register 2x2 pool + relu -> s2u bf16.
  // M-index m = pooledpos*4 + quadrant (pool-morton); wave wid: nth=wid>>1, mtg=wid&1.
  {
    const int lane = t & 63, wid = t >> 6;
    const int ln15 = lane & 15, quad = lane >> 4;
    const int nth = wid >> 1, mtg = wid & 1;
    const int nmt = mtg ? 6 : 7;                 // mt = mtg + 2k, 13 tiles total
    const int nt0 = nth * 2;
    int abase[7];
    #pragma unroll
    for (int k = 0; k < 7; ++k) {
      int mt = mtg + 2 * k;
      int m = mt * 16 + ln15;
      int pp = m >> 2; if (pp > 48) pp = 48;     // clamp pad rows (discarded)
      int qq = m & 3;
      int py = pp / 7, px = pp - py * 7;
      int oy = 2 * py + (qq >> 1), ox = 2 * px + (qq & 1);
      abase[k] = (oy * 16 + ox) * 80 + quad * 16; // +tapoff*80; grid row=(oy+ky)*16+ox+kx
    }
    const float bia0 = b2g[nt0 * 16 + ln15];
    const float bia1 = b2g[(nt0 + 1) * 16 + ln15];
    f32x4 acc[7][2];
    #pragma unroll
    for (int k = 0; k < 7; ++k) {
      acc[k][0] = (f32x4){bia0, bia0, bia0, bia0};
      acc[k][1] = (f32x4){bia1, bia1, bia1, bia1};
    }
    const char* s1b = (const char*)s1u;
    #pragma unroll 1
    for (int tap = 0; tap < 9; ++tap) {
      int ky = tap / 3, kx = tap - (tap / 3) * 3;
      const ushortT* bp = wsu + (tap * 64 + nt0 * 16 + ln15) * 32 + quad * 8;
      bf16x8 bh0 = *(const bf16x8*)bp;
      bf16x8 bl0 = *(const bf16x8*)(bp + 18432);
      bf16x8 bh1 = *(const bf16x8*)(bp + 512);
      bf16x8 bl1 = *(const bf16x8*)(bp + 18432 + 512);
      int soff = (ky * 16 + kx) * 80;
      #pragma unroll
      for (int k = 0; k < 7; ++k) {
        if (k < nmt) {
          bf16x8 a = *(const bf16x8*)(s1b + abase[k] + soff);
          acc[k][0] = __builtin_amdgcn_mfma_f32_16x16x32_bf16(a, bh0, acc[k][0], 0, 0, 0);
          acc[k][0] = __builtin_amdgcn_mfma_f32_16x16x32_bf16(a, bl0, acc[k][0], 0, 0, 0);
          acc[k][1] = __builtin_amdgcn_mfma_f32_16x16x32_bf16(a, bh1, acc[k][1], 0, 0, 0);
          acc[k][1] = __builtin_amdgcn_mfma_f32_16x16x32_bf16(a, bl1, acc[k][1], 0, 0, 0);
        }
      }
    }
    // D-reg r = pool quadrant; pooled pos pp = mt*4 + quad; col = nt*16+ln15
    #pragma unroll
    for (int k = 0; k < 7; ++k) {
      if (k < nmt) {
        int mt = mtg + 2 * k;
        int pp = mt * 4 + quad;
        if (pp < 49) {
          int py = pp / 7, px = pp - py * 7;
          int grow = (py + 1) * 9 + px + 1;
          f32x4 v0 = acc[k][0], v1 = acc[k][1];
          float p0 = fmaxf(fmaxf(v0.x, v0.y), fmaxf(v0.z, v0.w));
          float p1 = fmaxf(fmaxf(v1.x, v1.y), fmaxf(v1.z, v1.w));
          s2u[grow * 72 + nt0 * 16 + ln15]        = f2bf(fmaxf(p0, 0.f));
          s2u[grow * 72 + (nt0 + 1) * 16 + ln15]  = f2bf(fmaxf(p1, 0.f));
        }
      }
    }
  }
  __syncthreads();

  // stage 3: conv3 (64->64) via MFMA + relu. M = 49 positions pad 64 (4 mt), wave = nt.
  {
    const int lane = t & 63, wid = t >> 6;       // wid = nt
    const int ln15 = lane & 15, quad = lane >> 4;
    int abase2[4];
    #pragma unroll
    for (int mt = 0; mt < 4; ++mt) {
      int op = mt * 16 + ln15; if (op > 48) op = 48;
      int oy = op / 7, ox = op - (op / 7) * 7;
      abase2[mt] = (oy * 9 + ox) * 144 + quad * 16;
    }
    const float bia = b3g[wid * 16 + ln15];
    f32x4 acc3[4];
    #pragma unroll
    for (int mt = 0; mt < 4; ++mt) acc3[mt] = (f32x4){bia, bia, bia, bia};
    const char* s2b = (const char*)s2u;
    #pragma unroll 1
    for (int tap = 0; tap < 9; ++tap) {
      int ky = tap / 3, kx = tap - (tap / 3) * 3;
      const ushortT* bp = wsu + 36864 + (tap * 64 + wid * 16 + ln15) * 64 + quad * 8;
      #pragma unroll
      for (int kc = 0; kc < 2; ++kc) {
        bf16x8 bh = *(const bf16x8*)(bp + kc * 32);
        bf16x8 bl = *(const bf16x8*)(bp + 36864 + kc * 32);
        int soff = (ky * 9 + kx) * 144 + kc * 64;
        #pragma unroll
        for (int mt = 0; mt < 4; ++mt) {
          bf16x8 a = *(const bf16x8*)(s2b + abase2[mt] + soff);
          acc3[mt] = __builtin_amdgcn_mfma_f32_16x16x32_bf16(a, bh, acc3[mt], 0, 0, 0);
          acc3[mt] = __builtin_amdgcn_mfma_f32_16x16x32_bf16(a, bl, acc3[mt], 0, 0, 0);
        }
      }
    }
    if (DENSE_IN) {
      float* s3f = fregion;                      // xin dead; flat [op*64+co]
      #pragma unroll
      for (int mt = 0; mt < 4; ++mt)
        #pragma unroll
        for (int r = 0; r < 4; ++r) {
          int op = mt * 16 + quad * 4 + r;
          if (op < 49) s3f[op * 64 + wid * 16 + ln15] = fmaxf(acc3[mt][r], 0.f);
        }
    } else {
      float* dst = s3g + (long)b * 3136 + wid * 16 + ln15;
      #pragma unroll
      for (int mt = 0; mt < 4; ++mt)
        #pragma unroll
        for (int r = 0; r < 4; ++r) {
          int op = mt * 16 + quad * 4 + r;
          if (op < 49) dst[op * 64] = fmaxf(acc3[mt][r], 0.f);
        }
    }
  }

  if (DENSE_IN) {
    __syncthreads();
    float* s3f = fregion;
    float* red = fregion + 3136;
    float* hv  = fregion + 3136 + 1024;
    float* lg  = fregion + 3136 + 1088;
    float* le  = fregion + 3136 + 1098;
    {
      const int oq = (t & 15) * 4, kp = t >> 4;
      const float* wp = wd1g + (long)kp * 196 * 64 + oq;
      const float* ap = s3f + kp * 196;
      float a0 = 0.f, a1 = 0.f, a2 = 0.f, a3 = 0.f;
      #pragma unroll 4
      for (int k = 0; k < 196; ++k) {
        float a = ap[k];
        const float4 w = *(const float4*)(wp + (long)k * 64);
        a0 = fmaf(a, w.x, a0); a1 = fmaf(a, w.y, a1);
        a2 = fmaf(a, w.z, a2); a3 = fmaf(a, w.w, a3);
      }
      *(float4*)(red + kp * 64 + oq) = make_float4(a0, a1, a2, a3);
    }
    __syncthreads();
    if (t < 64) {
      float s = bd1g[t];
      #pragma unroll
      for (int kp = 0; kp < 16; ++kp) s += red[kp * 64 + t];
      hv[t] = fmaxf(s, 0.f);
    }
    __syncthreads();
    if (t < 10) {
      float a = bd2g[t];
      #pragma unroll
      for (int k = 0; k < 64; ++k) a = fmaf(hv[k], wd2g[k * 10 + t], a);
      lg[t] = a;
    }
    __syncthreads();
    if (t < 10) {
      float m = lg[0];
      #pragma unroll
      for (int i = 1; i < 10; ++i) m = fmaxf(m, lg[i]);
      le[t] = expf(lg[t] - m);
    }
    __syncthreads();
    if (t < 10) {
      float s = 0.f;
      #pragma unroll
      for (int i = 0; i < 10; ++i) s += le[i];
      out[(long)b * 10 + t] = le[t] / s;
    }
  }
}

// ---- dense head: 256 blocks x 8 images, 512 threads (wave g = image g)
__global__ __launch_bounds__(512) void dense_head(
    const float* __restrict__ s3g, const float* __restrict__ wd1g,
    const float* __restrict__ bd1g, const float* __restrict__ wd2g,
    const float* __restrict__ bd2g, float* __restrict__ out)
{
  __shared__ float hv[8 * 64];
  __shared__ float lgle[8 * 24];
  const int t = threadIdx.x;
  const int o = t & 63, g = t >> 6;
  const long img = (long)blockIdx.x * 8 + g;
  const float* xv = s3g + img * 3136;
  const float* wp = wd1g + o;
  float a = 0.f;
  #pragma unroll 8
  for (int k = 0; k < 3136; ++k)
    a = fmaf(xv[k], wp[(long)k * 64], a);
  hv[g * 64 + o] = fmaxf(a + bd1g[o], 0.f);
  __syncthreads();
  float* lg = lgle;
  float* le = lgle + 96;
  if (t < 80) {
    int im = t / 10, c = t - im * 10;
    float acc = bd2g[c];
    #pragma unroll
    for (int k = 0; k < 64; ++k) acc = fmaf(hv[im * 64 + k], wd2g[k * 10 + c], acc);
    lg[im * 12 + c] = acc;
  }
  __syncthreads();
  if (t < 80) {
    int im = t / 10, c = t - im * 10;
    float m = lg[im * 12];
    #pragma unroll
    for (int i = 1; i < 10; ++i) m = fmaxf(m, lg[im * 12 + i]);
    le[im * 12 + c] = expf(lg[im * 12 + c] - m);
  }
  __syncthreads();
  if (t < 80) {
    int im = t / 10, c = t - im * 10;
    float s = 0.f;
    #pragma unroll
    for (int i = 0; i < 10; ++i) s += le[im * 12 + i];
    out[((long)blockIdx.x * 8 + im) * 10 + c] = le[im * 12 + c] / s;
  }
}

extern "C" void kernel_launch(void* const* d_in, const int* in_sizes, int n_in,
                              void* d_out, int out_size, void* d_ws, size_t ws_size,
                              hipStream_t stream) {
  (void)in_sizes; (void)n_in; (void)out_size;
  const float* x   = (const float*)d_in[0];
  const float* w1  = (const float*)d_in[1];
  const float* b1  = (const float*)d_in[2];
  const float* w2  = (const float*)d_in[3];
  const float* b2  = (const float*)d_in[4];
  const float* w3  = (const float*)d_in[5];
  const float* b3  = (const float*)d_in[6];
  const float* wd1 = (const float*)d_in[7];
  const float* bd1 = (const float*)d_in[8];
  const float* wd2 = (const float*)d_in[9];
  const float* bd2 = (const float*)d_in[10];
  float* out = (float*)d_out;
  ushortT* wsu = (ushortT*)d_ws;
  const size_t need_w = 221184;                       // split weights
  const size_t need_full = need_w + (size_t)NBATCH * 3136 * 4;

  hipLaunchKernelGGL(prep_w, dim3(216), dim3(256), 0, stream, w2, w3, wsu);
  if (ws_size >= need_full) {
    float* s3g = (float*)((char*)d_ws + need_w);
    hipLaunchKernelGGL((conv_fused<false>), dim3(NBATCH), dim3(256), 0, stream,
                       x, w1, b1, b2, b3, wsu, s3g, wd1, bd1, wd2, bd2, out);
    hipLaunchKernelGGL(dense_head, dim3(NBATCH / 8), dim3(512), 0, stream,
                       s3g, wd1, bd1, wd2, bd2, out);
  } else {
    hipLaunchKernelGGL((conv_fused<true>), dim3(NBATCH), dim3(256), 0, stream,
                       x, w1, b1, b2, b3, wsu, (float*)nullptr, wd1, bd1, wd2, bd2, out);
  }
}

// Round 4
// 194.081 us; speedup vs baseline: 3.9427x; 1.3532x over previous
//
#include <hip/hip_runtime.h>
#include <math.h>

#define NBATCH 2048

typedef unsigned short ushortT;
typedef __attribute__((ext_vector_type(8))) short bf16x8;
typedef __attribute__((ext_vector_type(4))) float f32x4;

__device__ __forceinline__ ushortT f2bf(float f) {
  union { float f; unsigned u; } v; v.f = f;
  unsigned r = v.u + 0x7FFF + ((v.u >> 16) & 1);
  return (ushortT)(r >> 16);
}
__device__ __forceinline__ float bf2f(ushortT h) {
  union { float f; unsigned u; } v; v.u = ((unsigned)h) << 16; return v.f;
}

// ws ushort layout:
//   w2t_hi [0,18432)  w2t_lo [18432,36864)        [tap][co][ci]
//   w3t_hi [36864,73728) w3t_lo [73728,110592)    [tap][co][ci]
//   wd1t_hi [110592,311296) wd1t_lo [311296,512000)  [co][ci]
//   s3 bf16 [512000, 512000+2048*3136)            [img][op*64+co]
#define WD1T_HI 110592
#define WD1T_LO 311296
#define S3_OFF  512000

__global__ __launch_bounds__(256) void prep_w(const float* __restrict__ w2,
                                              const float* __restrict__ w3,
                                              const float* __restrict__ wd1,
                                              ushortT* __restrict__ ws) {
  int i = blockIdx.x * 256 + threadIdx.x;
  if (i < 18432) {
    int tap = i / 2048, r = i - tap * 2048, ci = r >> 6, co = r & 63;
    float w = w2[i];
    ushortT hb = f2bf(w);
    ushortT lb = f2bf(w - bf2f(hb));
    int o = (tap * 64 + co) * 32 + ci;
    ws[o] = hb; ws[18432 + o] = lb;
  } else if (i < 55296) {
    int j = i - 18432;
    int tap = j >> 12, r = j & 4095, ci = r >> 6, co = r & 63;
    float w = w3[j];
    ushortT hb = f2bf(w);
    ushortT lb = f2bf(w - bf2f(hb));
    int o = (tap * 64 + co) * 64 + ci;
    ws[36864 + o] = hb; ws[73728 + o] = lb;
  } else if (i < 256000) {
    int j = i - 55296;                  // j = ci*64 + co
    int ci = j >> 6, co = j & 63;
    float w = wd1[j];
    ushortT hb = f2bf(w);
    ushortT lb = f2bf(w - bf2f(hb));
    int o = co * 3136 + ci;
    ws[WD1T_HI + o] = hb; ws[WD1T_LO + o] = lb;
  }
}

// ---- fused conv1+pool (fp32) -> conv2+pool (MFMA) -> conv3 (MFMA), s3 -> global bf16
__global__ __launch_bounds__(256, 4) void conv_fused(
    const float* __restrict__ xg,
    const float* __restrict__ w1g, const float* __restrict__ b1g,
    const float* __restrict__ b2g, const float* __restrict__ b3g,
    const ushortT* __restrict__ wsu, ushortT* __restrict__ s3g)
{
  __shared__ __align__(16) ushortT s1u[240 * 40];   // zero-halo [row16(iy+1)+ix+1][40]
  __shared__ __align__(16) ushortT s2u[81 * 72];    // zero-halo [row9(iy+1)+ix+1][72]
  __shared__ __align__(16) float xin[930];          // [30][31] zero-padded

  const int t = threadIdx.x, b = blockIdx.x;

  {
    unsigned* p1 = (unsigned*)s1u;
    unsigned* p2 = (unsigned*)s2u;
    for (int i = t; i < 4800; i += 256) p1[i] = 0u;
    for (int i = t; i < 2916; i += 256) p2[i] = 0u;
    for (int i = t; i < 930;  i += 256) xin[i] = 0.f;
  }
  __syncthreads();
  const float* xb = xg + (long)b * 784;
  for (int i = t; i < 784; i += 256) {
    int y = i / 28, x = i - y * 28;
    xin[(y + 1) * 31 + (x + 1)] = xb[i];
  }
  __syncthreads();

  // stage 1: conv1 (1->32) + relu + pool -> s1u bf16
  {
    const int c = t & 31, pg = t >> 5;
    float wr[9];
    #pragma unroll
    for (int j = 0; j < 9; ++j) wr[j] = w1g[j * 32 + c];
    const float bias = b1g[c];
    for (int p = pg; p < 196; p += 8) {
      int oy = p / 14, ox = p - oy * 14;
      int base = (2 * oy) * 31 + 2 * ox;
      float xw[16];
      #pragma unroll
      for (int r = 0; r < 4; ++r)
        #pragma unroll
        for (int cc = 0; cc < 4; ++cc) xw[r * 4 + cc] = xin[base + r * 31 + cc];
      float m = 0.f;
      #pragma unroll
      for (int dy = 0; dy < 2; ++dy)
      #pragma unroll
      for (int dx = 0; dx < 2; ++dx) {
        float acc = bias;
        #pragma unroll
        for (int ky = 0; ky < 3; ++ky)
        #pragma unroll
        for (int kx = 0; kx < 3; ++kx)
          acc = fmaf(xw[(dy + ky) * 4 + (dx + kx)], wr[ky * 3 + kx], acc);
        m = fmaxf(m, acc);
      }
      s1u[((oy + 1) * 16 + ox + 1) * 40 + c] = f2bf(m);
    }
  }
  __syncthreads();

  // stage 2: conv2 (32->64) MFMA, pool-morton M; in-register 2x2 pool + relu -> s2u
  {
    const int lane = t & 63, wid = t >> 6;
    const int ln15 = lane & 15, quad = lane >> 4;
    const int nth = wid >> 1, mtg = wid & 1;
    const int nmt = mtg ? 6 : 7;
    const int nt0 = nth * 2;
    int abase[7];
    #pragma unroll
    for (int k = 0; k < 7; ++k) {
      int mt = mtg + 2 * k;
      int m = mt * 16 + ln15;
      int pp = m >> 2; if (pp > 48) pp = 48;
      int qq = m & 3;
      int py = pp / 7, px = pp - py * 7;
      int oy = 2 * py + (qq >> 1), ox = 2 * px + (qq & 1);
      abase[k] = (oy * 16 + ox) * 80 + quad * 16;
    }
    const float bia0 = b2g[nt0 * 16 + ln15];
    const float bia1 = b2g[(nt0 + 1) * 16 + ln15];
    f32x4 acc[7][2];
    #pragma unroll
    for (int k = 0; k < 7; ++k) {
      acc[k][0] = (f32x4){bia0, bia0, bia0, bia0};
      acc[k][1] = (f32x4){bia1, bia1, bia1, bia1};
    }
    const char* s1b = (const char*)s1u;
    #pragma unroll 1
    for (int tap = 0; tap < 9; ++tap) {
      int ky = tap / 3, kx = tap - (tap / 3) * 3;
      const ushortT* bp = wsu + (tap * 64 + nt0 * 16 + ln15) * 32 + quad * 8;
      bf16x8 bh0 = *(const bf16x8*)bp;
      bf16x8 bl0 = *(const bf16x8*)(bp + 18432);
      bf16x8 bh1 = *(const bf16x8*)(bp + 512);
      bf16x8 bl1 = *(const bf16x8*)(bp + 18432 + 512);
      int soff = (ky * 16 + kx) * 80;
      #pragma unroll
      for (int k = 0; k < 7; ++k) {
        if (k < nmt) {
          bf16x8 a = *(const bf16x8*)(s1b + abase[k] + soff);
          acc[k][0] = __builtin_amdgcn_mfma_f32_16x16x32_bf16(a, bh0, acc[k][0], 0, 0, 0);
          acc[k][0] = __builtin_amdgcn_mfma_f32_16x16x32_bf16(a, bl0, acc[k][0], 0, 0, 0);
          acc[k][1] = __builtin_amdgcn_mfma_f32_16x16x32_bf16(a, bh1, acc[k][1], 0, 0, 0);
          acc[k][1] = __builtin_amdgcn_mfma_f32_16x16x32_bf16(a, bl1, acc[k][1], 0, 0, 0);
        }
      }
    }
    #pragma unroll
    for (int k = 0; k < 7; ++k) {
      if (k < nmt) {
        int mt = mtg + 2 * k;
        int pp = mt * 4 + quad;
        if (pp < 49) {
          int py = pp / 7, px = pp - py * 7;
          int grow = (py + 1) * 9 + px + 1;
          f32x4 v0 = acc[k][0], v1 = acc[k][1];
          float p0 = fmaxf(fmaxf(v0.x, v0.y), fmaxf(v0.z, v0.w));
          float p1 = fmaxf(fmaxf(v1.x, v1.y), fmaxf(v1.z, v1.w));
          s2u[grow * 72 + nt0 * 16 + ln15]       = f2bf(fmaxf(p0, 0.f));
          s2u[grow * 72 + (nt0 + 1) * 16 + ln15] = f2bf(fmaxf(p1, 0.f));
        }
      }
    }
  }
  __syncthreads();

  // stage 3: conv3 (64->64) MFMA + relu -> s3g bf16
  {
    const int lane = t & 63, wid = t >> 6;
    const int ln15 = lane & 15, quad = lane >> 4;
    int abase2[4];
    #pragma unroll
    for (int mt = 0; mt < 4; ++mt) {
      int op = mt * 16 + ln15; if (op > 48) op = 48;
      int oy = op / 7, ox = op - (op / 7) * 7;
      abase2[mt] = (oy * 9 + ox) * 144 + quad * 16;
    }
    const float bia = b3g[wid * 16 + ln15];
    f32x4 acc3[4];
    #pragma unroll
    for (int mt = 0; mt < 4; ++mt) acc3[mt] = (f32x4){bia, bia, bia, bia};
    const char* s2b = (const char*)s2u;
    #pragma unroll 1
    for (int tap = 0; tap < 9; ++tap) {
      int ky = tap / 3, kx = tap - (tap / 3) * 3;
      const ushortT* bp = wsu + 36864 + (tap * 64 + wid * 16 + ln15) * 64 + quad * 8;
      #pragma unroll
      for (int kc = 0; kc < 2; ++kc) {
        bf16x8 bh = *(const bf16x8*)(bp + kc * 32);
        bf16x8 bl = *(const bf16x8*)(bp + 36864 + kc * 32);
        int soff = (ky * 9 + kx) * 144 + kc * 64;
        #pragma unroll
        for (int mt = 0; mt < 4; ++mt) {
          bf16x8 a = *(const bf16x8*)(s2b + abase2[mt] + soff);
          acc3[mt] = __builtin_amdgcn_mfma_f32_16x16x32_bf16(a, bh, acc3[mt], 0, 0, 0);
          acc3[mt] = __builtin_amdgcn_mfma_f32_16x16x32_bf16(a, bl, acc3[mt], 0, 0, 0);
        }
      }
    }
    ushortT* dst = s3g + (long)b * 3136 + wid * 16 + ln15;
    #pragma unroll
    for (int mt = 0; mt < 4; ++mt)
      #pragma unroll
      for (int r = 0; r < 4; ++r) {
        int op = mt * 16 + quad * 4 + r;
        if (op < 49) dst[op * 64] = f2bf(fmaxf(acc3[mt][r], 0.f));
      }
  }
}

// ---- dense1 (MFMA) + dense2 + softmax. 128 blocks x 16 images; wave = 16-ch n-tile.
__global__ __launch_bounds__(256) void dense_mfma(
    const ushortT* __restrict__ ws, const float* __restrict__ bd1g,
    const float* __restrict__ wd2g, const float* __restrict__ bd2g,
    float* __restrict__ out)
{
  __shared__ float hv[16 * 64];
  __shared__ float lgle[16 * 24];
  const int t = threadIdx.x;
  const int lane = t & 63, wid = t >> 6;
  const int ln15 = lane & 15, quad = lane >> 4;
  const int m0 = blockIdx.x * 16;
  const int n0 = wid * 16;

  const ushortT* s3 = ws + S3_OFF;
  const ushortT* ap = s3 + (long)(m0 + ln15) * 3136 + quad * 8;
  const ushortT* bh = ws + WD1T_HI + (long)(n0 + ln15) * 3136 + quad * 8;
  const ushortT* bl = ws + WD1T_LO + (long)(n0 + ln15) * 3136 + quad * 8;

  f32x4 acc = (f32x4){0.f, 0.f, 0.f, 0.f};
  #pragma unroll 2
  for (int kk = 0; kk < 98; ++kk) {
    bf16x8 a  = *(const bf16x8*)(ap + kk * 32);
    bf16x8 wh = *(const bf16x8*)(bh + kk * 32);
    bf16x8 wl = *(const bf16x8*)(bl + kk * 32);
    acc = __builtin_amdgcn_mfma_f32_16x16x32_bf16(a, wh, acc, 0, 0, 0);
    acc = __builtin_amdgcn_mfma_f32_16x16x32_bf16(a, wl, acc, 0, 0, 0);
  }
  const float bias = bd1g[n0 + ln15];
  #pragma unroll
  for (int r = 0; r < 4; ++r)
    hv[(quad * 4 + r) * 64 + n0 + ln15] = fmaxf(acc[r] + bias, 0.f);
  __syncthreads();

  float* lg = lgle;
  float* le = lgle + 192;
  if (t < 160) {
    int im = t / 10, c = t - im * 10;
    float a = bd2g[c];
    #pragma unroll
    for (int k = 0; k < 64; ++k) a = fmaf(hv[im * 64 + k], wd2g[k * 10 + c], a);
    lg[im * 12 + c] = a;
  }
  __syncthreads();
  if (t < 160) {
    int im = t / 10, c = t - im * 10;
    float m = lg[im * 12];
    #pragma unroll
    for (int i = 1; i < 10; ++i) m = fmaxf(m, lg[im * 12 + i]);
    le[im * 12 + c] = expf(lg[im * 12 + c] - m);
  }
  __syncthreads();
  if (t < 160) {
    int im = t / 10, c = t - im * 10;
    float s = 0.f;
    #pragma unroll
    for (int i = 0; i < 10; ++i) s += le[im * 12 + i];
    out[(long)(m0 + im) * 10 + c] = le[im * 12 + c] / s;
  }
}

extern "C" void kernel_launch(void* const* d_in, const int* in_sizes, int n_in,
                              void* d_out, int out_size, void* d_ws, size_t ws_size,
                              hipStream_t stream) {
  (void)in_sizes; (void)n_in; (void)out_size; (void)ws_size;
  const float* x   = (const float*)d_in[0];
  const float* w1  = (const float*)d_in[1];
  const float* b1  = (const float*)d_in[2];
  const float* w2  = (const float*)d_in[3];
  const float* b2  = (const float*)d_in[4];
  const float* w3  = (const float*)d_in[5];
  const float* b3  = (const float*)d_in[6];
  const float* wd1 = (const float*)d_in[7];
  const float* bd1 = (const float*)d_in[8];
  const float* wd2 = (const float*)d_in[9];
  const float* bd2 = (const float*)d_in[10];
  float* out = (float*)d_out;
  ushortT* wsu = (ushortT*)d_ws;
  ushortT* s3g = wsu + S3_OFF;

  hipLaunchKernelGGL(prep_w, dim3(1000), dim3(256), 0, stream, w2, w3, wd1, wsu);
  hipLaunchKernelGGL(conv_fused, dim3(NBATCH), dim3(256), 0, stream,
                     x, w1, b1, b2, b3, wsu, s3g);
  hipLaunchKernelGGL(dense_mfma, dim3(NBATCH / 16), dim3(256), 0, stream,
                     wsu, bd1, wd2, bd2, out);
}

// Round 5
// 180.755 us; speedup vs baseline: 4.2333x; 1.0737x over previous
//
#include <hip/hip_runtime.h>
#include <math.h>

#define NBATCH 2048

typedef unsigned short ushortT;
typedef __attribute__((ext_vector_type(8))) short bf16x8;
typedef __attribute__((ext_vector_type(4))) float f32x4;

__device__ __forceinline__ ushortT f2bf(float f) {
  union { float f; unsigned u; } v; v.f = f;
  unsigned r = v.u + 0x7FFF + ((v.u >> 16) & 1);
  return (ushortT)(r >> 16);
}
__device__ __forceinline__ float bf2f(ushortT h) {
  union { float f; unsigned u; } v; v.u = ((unsigned)h) << 16; return v.f;
}

// ws ushort layout:
//   w2t_hi [0,18432)  w2t_lo [18432,36864)        [tap][co][ci]
//   w3t_hi [36864,73728) w3t_lo [73728,110592)    [tap][co][ci]
//   wd1t_hi [110592,311296) wd1t_lo [311296,512000)  [co][ci]
//   s3 bf16 [512000, 512000+2048*3136)            [img][op*64+co]
#define WD1T_HI 110592
#define WD1T_LO 311296
#define S3_OFF  512000

__global__ __launch_bounds__(256) void prep_w(const float* __restrict__ w2,
                                              const float* __restrict__ w3,
                                              const float* __restrict__ wd1,
                                              ushortT* __restrict__ ws) {
  int i = blockIdx.x * 256 + threadIdx.x;
  if (i < 18432) {
    int tap = i / 2048, r = i - tap * 2048, ci = r >> 6, co = r & 63;
    float w = w2[i];
    ushortT hb = f2bf(w);
    ushortT lb = f2bf(w - bf2f(hb));
    int o = (tap * 64 + co) * 32 + ci;
    ws[o] = hb; ws[18432 + o] = lb;
  } else if (i < 55296) {
    int j = i - 18432;
    int tap = j >> 12, r = j & 4095, ci = r >> 6, co = r & 63;
    float w = w3[j];
    ushortT hb = f2bf(w);
    ushortT lb = f2bf(w - bf2f(hb));
    int o = (tap * 64 + co) * 64 + ci;
    ws[36864 + o] = hb; ws[73728 + o] = lb;
  } else if (i < 256000) {
    int j = i - 55296;                  // j = ci*64 + co
    int ci = j >> 6, co = j & 63;
    float w = wd1[j];
    ushortT hb = f2bf(w);
    ushortT lb = f2bf(w - bf2f(hb));
    int o = co * 3136 + ci;
    ws[WD1T_HI + o] = hb; ws[WD1T_LO + o] = lb;
  }
}

// ---- fused conv1+pool (fp32) -> conv2+pool (MFMA) -> conv3 (MFMA), s3 -> global bf16
__global__ __launch_bounds__(256, 4) void conv_fused(
    const float* __restrict__ xg,
    const float* __restrict__ w1g, const float* __restrict__ b1g,
    const float* __restrict__ b2g, const float* __restrict__ b3g,
    const ushortT* __restrict__ wsu, ushortT* __restrict__ s3g)
{
  __shared__ __align__(16) ushortT s1u[256 * 40];   // zero-halo [(iy+1)*16+ix+1][40]
  __shared__ __align__(16) ushortT s2u[81 * 72];    // zero-halo [(iy+1)*9+ix+1][72]
  __shared__ __align__(16) float xin[930];          // [30][31] zero-padded

  const int t = threadIdx.x, b = blockIdx.x;

  {
    unsigned* p1 = (unsigned*)s1u;
    unsigned* p2 = (unsigned*)s2u;
    for (int i = t; i < 5120; i += 256) p1[i] = 0u;
    for (int i = t; i < 2916; i += 256) p2[i] = 0u;
    for (int i = t; i < 930;  i += 256) xin[i] = 0.f;
  }
  __syncthreads();
  const float* xb = xg + (long)b * 784;
  for (int i = t; i < 784; i += 256) {
    int y = i / 28, x = i - y * 28;
    xin[(y + 1) * 31 + (x + 1)] = xb[i];
  }
  __syncthreads();

  // stage 1: conv1 (1->32) + relu + pool -> s1u bf16
  {
    const int c = t & 31, pg = t >> 5;
    float wr[9];
    #pragma unroll
    for (int j = 0; j < 9; ++j) wr[j] = w1g[j * 32 + c];
    const float bias = b1g[c];
    for (int p = pg; p < 196; p += 8) {
      int oy = p / 14, ox = p - oy * 14;
      int base = (2 * oy) * 31 + 2 * ox;
      float xw[16];
      #pragma unroll
      for (int r = 0; r < 4; ++r)
        #pragma unroll
        for (int cc = 0; cc < 4; ++cc) xw[r * 4 + cc] = xin[base + r * 31 + cc];
      float m = 0.f;
      #pragma unroll
      for (int dy = 0; dy < 2; ++dy)
      #pragma unroll
      for (int dx = 0; dx < 2; ++dx) {
        float acc = bias;
        #pragma unroll
        for (int ky = 0; ky < 3; ++ky)
        #pragma unroll
        for (int kx = 0; kx < 3; ++kx)
          acc = fmaf(xw[(dy + ky) * 4 + (dx + kx)], wr[ky * 3 + kx], acc);
        m = fmaxf(m, acc);
      }
      s1u[((oy + 1) * 16 + ox + 1) * 40 + c] = f2bf(m);
    }
  }
  __syncthreads();

  // stage 2: conv2 (32->64) MFMA, pool-morton M; prefetched B; pool+relu -> s2u
  {
    const int lane = t & 63, wid = t >> 6;
    const int ln15 = lane & 15, quad = lane >> 4;
    const int nth = wid >> 1, mtg = wid & 1;
    const int nmt = mtg ? 6 : 7;
    const int nt0 = nth * 2;
    int abase[7];
    #pragma unroll
    for (int k = 0; k < 7; ++k) {
      int mt = mtg + 2 * k;
      int m = mt * 16 + ln15;
      int pp = m >> 2; if (pp > 48) pp = 48;
      int qq = m & 3;
      int py = pp / 7, px = pp - py * 7;
      int oy = 2 * py + (qq >> 1), ox = 2 * px + (qq & 1);
      abase[k] = (oy * 16 + ox) * 80 + quad * 16;
    }
    const float bia0 = b2g[nt0 * 16 + ln15];
    const float bia1 = b2g[(nt0 + 1) * 16 + ln15];
    f32x4 acc[7][2];
    #pragma unroll
    for (int k = 0; k < 7; ++k) {
      acc[k][0] = (f32x4){bia0, bia0, bia0, bia0};
      acc[k][1] = (f32x4){bia1, bia1, bia1, bia1};
    }
    const char* s1b = (const char*)s1u;
    const ushortT* wbase = wsu + (nt0 * 16 + ln15) * 32 + quad * 8;
    bf16x8 cur[4], nxt[4];
    {
      const ushortT* bp = wbase;
      cur[0] = *(const bf16x8*)bp;
      cur[1] = *(const bf16x8*)(bp + 18432);
      cur[2] = *(const bf16x8*)(bp + 512);
      cur[3] = *(const bf16x8*)(bp + 18432 + 512);
    }
    #pragma unroll 1
    for (int tap = 0; tap < 9; ++tap) {
      {
        int tn = tap < 8 ? tap + 1 : 8;
        const ushortT* bp = wbase + tn * 2048;
        nxt[0] = *(const bf16x8*)bp;
        nxt[1] = *(const bf16x8*)(bp + 18432);
        nxt[2] = *(const bf16x8*)(bp + 512);
        nxt[3] = *(const bf16x8*)(bp + 18432 + 512);
      }
      int ky = tap / 3, kx = tap - (tap / 3) * 3;
      int soff = (ky * 16 + kx) * 80;
      #pragma unroll
      for (int k = 0; k < 7; ++k) {
        if (k < nmt) {
          bf16x8 a = *(const bf16x8*)(s1b + abase[k] + soff);
          acc[k][0] = __builtin_amdgcn_mfma_f32_16x16x32_bf16(a, cur[0], acc[k][0], 0, 0, 0);
          acc[k][0] = __builtin_amdgcn_mfma_f32_16x16x32_bf16(a, cur[1], acc[k][0], 0, 0, 0);
          acc[k][1] = __builtin_amdgcn_mfma_f32_16x16x32_bf16(a, cur[2], acc[k][1], 0, 0, 0);
          acc[k][1] = __builtin_amdgcn_mfma_f32_16x16x32_bf16(a, cur[3], acc[k][1], 0, 0, 0);
        }
      }
      #pragma unroll
      for (int i = 0; i < 4; ++i) cur[i] = nxt[i];
    }
    #pragma unroll
    for (int k = 0; k < 7; ++k) {
      if (k < nmt) {
        int mt = mtg + 2 * k;
        int pp = mt * 4 + quad;
        if (pp < 49) {
          int py = pp / 7, px = pp - py * 7;
          int grow = (py + 1) * 9 + px + 1;
          f32x4 v0 = acc[k][0], v1 = acc[k][1];
          float p0 = fmaxf(fmaxf(v0.x, v0.y), fmaxf(v0.z, v0.w));
          float p1 = fmaxf(fmaxf(v1.x, v1.y), fmaxf(v1.z, v1.w));
          s2u[grow * 72 + nt0 * 16 + ln15]       = f2bf(fmaxf(p0, 0.f));
          s2u[grow * 72 + (nt0 + 1) * 16 + ln15] = f2bf(fmaxf(p1, 0.f));
        }
      }
    }
  }
  __syncthreads();

  // stage 3: conv3 (64->64) MFMA + relu, prefetched B -> s3g bf16
  {
    const int lane = t & 63, wid = t >> 6;
    const int ln15 = lane & 15, quad = lane >> 4;
    int abase2[4];
    #pragma unroll
    for (int mt = 0; mt < 4; ++mt) {
      int op = mt * 16 + ln15; if (op > 48) op = 48;
      int oy = op / 7, ox = op - (op / 7) * 7;
      abase2[mt] = (oy * 9 + ox) * 144 + quad * 16;
    }
    const float bia = b3g[wid * 16 + ln15];
    f32x4 acc3[4];
    #pragma unroll
    for (int mt = 0; mt < 4; ++mt) acc3[mt] = (f32x4){bia, bia, bia, bia};
    const char* s2b = (const char*)s2u;
    const ushortT* w3base = wsu + 36864 + (wid * 16 + ln15) * 64 + quad * 8;
    bf16x8 cur[4], nxt[4];
    {
      const ushortT* bp = w3base;
      cur[0] = *(const bf16x8*)bp;
      cur[1] = *(const bf16x8*)(bp + 36864);
      cur[2] = *(const bf16x8*)(bp + 32);
      cur[3] = *(const bf16x8*)(bp + 36864 + 32);
    }
    #pragma unroll 1
    for (int tap = 0; tap < 9; ++tap) {
      {
        int tn = tap < 8 ? tap + 1 : 8;
        const ushortT* bp = w3base + tn * 4096;
        nxt[0] = *(const bf16x8*)bp;
        nxt[1] = *(const bf16x8*)(bp + 36864);
        nxt[2] = *(const bf16x8*)(bp + 32);
        nxt[3] = *(const bf16x8*)(bp + 36864 + 32);
      }
      int ky = tap / 3, kx = tap - (tap / 3) * 3;
      int soff = (ky * 9 + kx) * 144;
      #pragma unroll
      for (int kc = 0; kc < 2; ++kc) {
        #pragma unroll
        for (int mt = 0; mt < 4; ++mt) {
          bf16x8 a = *(const bf16x8*)(s2b + abase2[mt] + soff + kc * 64);
          acc3[mt] = __builtin_amdgcn_mfma_f32_16x16x32_bf16(a, cur[kc * 2],     acc3[mt], 0, 0, 0);
          acc3[mt] = __builtin_amdgcn_mfma_f32_16x16x32_bf16(a, cur[kc * 2 + 1], acc3[mt], 0, 0, 0);
        }
      }
      #pragma unroll
      for (int i = 0; i < 4; ++i) cur[i] = nxt[i];
    }
    ushortT* dst = s3g + (long)b * 3136 + wid * 16 + ln15;
    #pragma unroll
    for (int mt = 0; mt < 4; ++mt)
      #pragma unroll
      for (int r = 0; r < 4; ++r) {
        int op = mt * 16 + quad * 4 + r;
        if (op < 49) dst[op * 64] = f2bf(fmaxf(acc3[mt][r], 0.f));
      }
  }
}

// ---- dense1 (MFMA, 4 n-tiles x 4 K-quarters = 16 waves) + dense2 + softmax.
__global__ __launch_bounds__(1024) void dense_mfma(
    const ushortT* __restrict__ ws, const float* __restrict__ bd1g,
    const float* __restrict__ wd2g, const float* __restrict__ bd2g,
    float* __restrict__ out)
{
  __shared__ float part[16 * 256];   // [(kq*4+nt)][im*16+c15]
  __shared__ float hv[16 * 64];
  __shared__ float lgle[16 * 24];
  const int t = threadIdx.x;
  const int lane = t & 63, wid = t >> 6;
  const int ln15 = lane & 15, quad = lane >> 4;
  const int nt = wid & 3, kq = wid >> 2;
  const int m0 = blockIdx.x * 16;
  const int n0 = nt * 16;
  const int ks = kq * 24 + (kq < 2 ? kq : 2);
  const int ke = ks + (kq < 2 ? 25 : 24);

  const ushortT* s3 = ws + S3_OFF;
  const ushortT* ap = s3 + (long)(m0 + ln15) * 3136 + quad * 8;
  const ushortT* bh = ws + WD1T_HI + (long)(n0 + ln15) * 3136 + quad * 8;
  const ushortT* bl = ws + WD1T_LO + (long)(n0 + ln15) * 3136 + quad * 8;

  f32x4 acc = (f32x4){0.f, 0.f, 0.f, 0.f};
  #pragma unroll 2
  for (int kk = ks; kk < ke; ++kk) {
    bf16x8 a  = *(const bf16x8*)(ap + kk * 32);
    bf16x8 wh = *(const bf16x8*)(bh + kk * 32);
    bf16x8 wl = *(const bf16x8*)(bl + kk * 32);
    acc = __builtin_amdgcn_mfma_f32_16x16x32_bf16(a, wh, acc, 0, 0, 0);
    acc = __builtin_amdgcn_mfma_f32_16x16x32_bf16(a, wl, acc, 0, 0, 0);
  }
  float* dst = part + (kq * 4 + nt) * 256;
  #pragma unroll
  for (int r = 0; r < 4; ++r)
    dst[(quad * 4 + r) * 16 + ln15] = acc[r];
  __syncthreads();

  {
    const int im = t >> 6, ch = t & 63;
    const int ntc = ch >> 4, c15 = ch & 15;
    float v = bd1g[ch];
    #pragma unroll
    for (int k2 = 0; k2 < 4; ++k2)
      v += part[(k2 * 4 + ntc) * 256 + im * 16 + c15];
    hv[im * 64 + ch] = fmaxf(v, 0.f);
  }
  __syncthreads();

  float* lg = lgle;
  float* le = lgle + 192;
  if (t < 160) {
    int im = t / 10, c = t - im * 10;
    float a = bd2g[c];
    #pragma unroll
    for (int k = 0; k < 64; ++k) a = fmaf(hv[im * 64 + k], wd2g[k * 10 + c], a);
    lg[im * 12 + c] = a;
  }
  __syncthreads();
  if (t < 160) {
    int im = t / 10, c = t - im * 10;
    float m = lg[im * 12];
    #pragma unroll
    for (int i = 1; i < 10; ++i) m = fmaxf(m, lg[im * 12 + i]);
    le[im * 12 + c] = expf(lg[im * 12 + c] - m);
  }
  __syncthreads();
  if (t < 160) {
    int im = t / 10, c = t - im * 10;
    float s = 0.f;
    #pragma unroll
    for (int i = 0; i < 10; ++i) s += le[im * 12 + i];
    out[(long)(m0 + im) * 10 + c] = le[im * 12 + c] / s;
  }
}

extern "C" void kernel_launch(void* const* d_in, const int* in_sizes, int n_in,
                              void* d_out, int out_size, void* d_ws, size_t ws_size,
                              hipStream_t stream) {
  (void)in_sizes; (void)n_in; (void)out_size; (void)ws_size;
  const float* x   = (const float*)d_in[0];
  const float* w1  = (const float*)d_in[1];
  const float* b1  = (const float*)d_in[2];
  const float* w2  = (const float*)d_in[3];
  const float* b2  = (const float*)d_in[4];
  const float* w3  = (const float*)d_in[5];
  const float* b3  = (const float*)d_in[6];
  const float* wd1 = (const float*)d_in[7];
  const float* bd1 = (const float*)d_in[8];
  const float* wd2 = (const float*)d_in[9];
  const float* bd2 = (const float*)d_in[10];
  float* out = (float*)d_out;
  ushortT* wsu = (ushortT*)d_ws;
  ushortT* s3g = wsu + S3_OFF;

  hipLaunchKernelGGL(prep_w, dim3(1000), dim3(256), 0, stream, w2, w3, wd1, wsu);
  hipLaunchKernelGGL(conv_fused, dim3(NBATCH), dim3(256), 0, stream,
                     x, w1, b1, b2, b3, wsu, s3g);
  hipLaunchKernelGGL(dense_mfma, dim3(NBATCH / 16), dim3(1024), 0, stream,
                     wsu, bd1, wd2, bd2, out);
}